// Round 1
// baseline (60.907 us; speedup 1.0000x reference)
//
#include <hip/hip_runtime.h>

#define NCLS 3
#define BLOCK 1024
#define NWAVES (BLOCK / 64)

// loss = 1e-4 + (1/B^2) * sum_k count[k] * sum_i |v[i,k]|
//   v[i,k] = eps*sum_c D[i,c] + (1-eps)*D[i,k]
//   D[i,c] = logT[i,c] - log_softmax(s)[i,c],  logT[i,c] = (c==t[i]) ? 0 : log(eps)
__global__ __launch_bounds__(BLOCK) void self_l2_kernel(
    const float* __restrict__ s, const int* __restrict__ t,
    float* __restrict__ out, int B) {
  constexpr float EPS = 1e-4f;
  constexpr float LOG_EPS = -9.210340371976182f;  // log(1e-4)
  constexpr float OME = 1.0f - EPS;

  double a0 = 0.0, a1 = 0.0, a2 = 0.0;   // A[k] partials
  double c0 = 0.0, c1 = 0.0, c2 = 0.0;   // count[k] partials

  for (int i = threadIdx.x; i < B; i += BLOCK) {
    const float s0 = s[3 * i + 0];
    const float s1 = s[3 * i + 1];
    const float s2 = s[3 * i + 2];
    const int ti = t[i];

    // log-softmax over 3 elements (max-subtracted, matches jax.nn.log_softmax)
    const float m = fmaxf(s0, fmaxf(s1, s2));
    const float lse = m + logf(expf(s0 - m) + expf(s1 - m) + expf(s2 - m));
    const float ls0 = s0 - lse, ls1 = s1 - lse, ls2 = s2 - lse;

    const float lt0 = (ti == 0) ? 0.0f : LOG_EPS;
    const float lt1 = (ti == 1) ? 0.0f : LOG_EPS;
    const float lt2 = (ti == 2) ? 0.0f : LOG_EPS;

    const float D0 = lt0 - ls0, D1 = lt1 - ls1, D2 = lt2 - ls2;
    const float sD = D0 + D1 + D2;

    a0 += (double)fabsf(EPS * sD + OME * D0);
    a1 += (double)fabsf(EPS * sD + OME * D1);
    a2 += (double)fabsf(EPS * sD + OME * D2);
    c0 += (ti == 0) ? 1.0 : 0.0;
    c1 += (ti == 1) ? 1.0 : 0.0;
    c2 += (ti == 2) ? 1.0 : 0.0;
  }

  // wave (64-lane) butterfly reduce of 6 doubles
  for (int off = 32; off > 0; off >>= 1) {
    a0 += __shfl_down(a0, off);
    a1 += __shfl_down(a1, off);
    a2 += __shfl_down(a2, off);
    c0 += __shfl_down(c0, off);
    c1 += __shfl_down(c1, off);
    c2 += __shfl_down(c2, off);
  }

  __shared__ double sm[NWAVES][6];
  const int lane = threadIdx.x & 63;
  const int wave = threadIdx.x >> 6;
  if (lane == 0) {
    sm[wave][0] = a0; sm[wave][1] = a1; sm[wave][2] = a2;
    sm[wave][3] = c0; sm[wave][4] = c1; sm[wave][5] = c2;
  }
  __syncthreads();

  if (threadIdx.x == 0) {
    double A0 = 0, A1 = 0, A2 = 0, C0 = 0, C1 = 0, C2 = 0;
    for (int w = 0; w < NWAVES; ++w) {
      A0 += sm[w][0]; A1 += sm[w][1]; A2 += sm[w][2];
      C0 += sm[w][3]; C1 += sm[w][4]; C2 += sm[w][5];
    }
    const double Bd = (double)B;
    const double loss = 1e-4 + (C0 * A0 + C1 * A1 + C2 * A2) / (Bd * Bd);
    out[0] = (float)loss;
  }
}

extern "C" void kernel_launch(void* const* d_in, const int* in_sizes, int n_in,
                              void* d_out, int out_size, void* d_ws, size_t ws_size,
                              hipStream_t stream) {
  const float* s = (const float*)d_in[0];
  const int* t = (const int*)d_in[1];
  float* out = (float*)d_out;
  const int B = in_sizes[0] / NCLS;
  self_l2_kernel<<<dim3(1), dim3(BLOCK), 0, stream>>>(s, t, out, B);
}

// Round 2
// 57.245 us; speedup vs baseline: 1.0640x; 1.0640x over previous
//
#include <hip/hip_runtime.h>

#define NCLS 3
#define K1_BLOCK 64   // one wave per block

// loss = 1e-4 + (1/B^2) * sum_k count[k] * A[k],  A[k] = sum_i |v[i,k]|
//   v[i,k] = eps*sum_c D[i,c] + (1-eps)*D[i,k]
//   D[i,c] = logT[i,c] - log_softmax(s)[i,c],  logT[i,c] = (c==t[i]) ? 0 : log(eps)
//
// Stage 1: each block (1 wave, 64 threads, 4 rows/thread via float4/int4 loads)
// reduces its slice to 6 doubles {A0,A1,A2,C0,C1,C2} -> ws[block*6 ..]
__device__ __forceinline__ void accum_row(float s0, float s1, float s2, int ti,
                                          double& a0, double& a1, double& a2,
                                          double& c0, double& c1, double& c2) {
  constexpr float EPS = 1e-4f;
  constexpr float LOG_EPS = -9.210340371976182f;  // log(1e-4)
  constexpr float OME = 1.0f - EPS;

  const float m = fmaxf(s0, fmaxf(s1, s2));
  const float lse = m + logf(expf(s0 - m) + expf(s1 - m) + expf(s2 - m));
  const float ls0 = s0 - lse, ls1 = s1 - lse, ls2 = s2 - lse;

  const float lt0 = (ti == 0) ? 0.0f : LOG_EPS;
  const float lt1 = (ti == 1) ? 0.0f : LOG_EPS;
  const float lt2 = (ti == 2) ? 0.0f : LOG_EPS;

  const float D0 = lt0 - ls0, D1 = lt1 - ls1, D2 = lt2 - ls2;
  const float sD = D0 + D1 + D2;

  a0 += (double)fabsf(EPS * sD + OME * D0);
  a1 += (double)fabsf(EPS * sD + OME * D1);
  a2 += (double)fabsf(EPS * sD + OME * D2);
  c0 += (ti == 0) ? 1.0 : 0.0;
  c1 += (ti == 1) ? 1.0 : 0.0;
  c2 += (ti == 2) ? 1.0 : 0.0;
}

__global__ __launch_bounds__(K1_BLOCK) void partial_kernel(
    const float* __restrict__ s, const int* __restrict__ t,
    double* __restrict__ ws, int B) {
  const int quanta = B >> 2;  // groups of 4 rows
  const int gtid = blockIdx.x * K1_BLOCK + threadIdx.x;
  const int gstride = gridDim.x * K1_BLOCK;

  double a0 = 0, a1 = 0, a2 = 0, c0 = 0, c1 = 0, c2 = 0;

  for (int j = gtid; j < quanta; j += gstride) {
    // 4 rows = 12 floats = 3 x float4 (16B-aligned: 48j % 16 == 0)
    const float4 f0 = ((const float4*)s)[3 * j + 0];
    const float4 f1 = ((const float4*)s)[3 * j + 1];
    const float4 f2 = ((const float4*)s)[3 * j + 2];
    const int4 tv = ((const int4*)t)[j];

    accum_row(f0.x, f0.y, f0.z, tv.x, a0, a1, a2, c0, c1, c2);
    accum_row(f0.w, f1.x, f1.y, tv.y, a0, a1, a2, c0, c1, c2);
    accum_row(f1.z, f1.w, f2.x, tv.z, a0, a1, a2, c0, c1, c2);
    accum_row(f2.y, f2.z, f2.w, tv.w, a0, a1, a2, c0, c1, c2);
  }

  // tail rows (B % 4), handled by global thread 0 (none for B=8192)
  if (gtid == 0) {
    for (int i = quanta << 2; i < B; ++i)
      accum_row(s[3 * i], s[3 * i + 1], s[3 * i + 2], t[i], a0, a1, a2, c0, c1, c2);
  }

  // wave butterfly reduce (single wave per block)
  for (int off = 32; off > 0; off >>= 1) {
    a0 += __shfl_down(a0, off);
    a1 += __shfl_down(a1, off);
    a2 += __shfl_down(a2, off);
    c0 += __shfl_down(c0, off);
    c1 += __shfl_down(c1, off);
    c2 += __shfl_down(c2, off);
  }

  if (threadIdx.x == 0) {
    double* p = ws + (size_t)blockIdx.x * 6;
    p[0] = a0; p[1] = a1; p[2] = a2;
    p[3] = c0; p[4] = c1; p[5] = c2;
  }
}

// Stage 2: one wave folds nb x 6 partials and writes the scalar loss.
// Lane l (l<48): accumulator c = l>>3, partial-block offset b0 = l&7.
__global__ __launch_bounds__(64) void finalize_kernel(
    const double* __restrict__ ws, float* __restrict__ out, int B, int nb) {
  const int l = threadIdx.x;
  const int c = l >> 3;
  const int b0 = l & 7;
  double v = 0.0;
  if (c < 6) {
    for (int b = b0; b < nb; b += 8) v += ws[b * 6 + c];
  }
  v += __shfl_down(v, 4, 8);
  v += __shfl_down(v, 2, 8);
  v += __shfl_down(v, 1, 8);
  // after width-8 reduce, lane 8*c holds the total for accumulator c
  const double A0 = __shfl(v, 0),  A1 = __shfl(v, 8),  A2 = __shfl(v, 16);
  const double C0 = __shfl(v, 24), C1 = __shfl(v, 32), C2 = __shfl(v, 40);
  if (l == 0) {
    const double Bd = (double)B;
    out[0] = (float)(1e-4 + (C0 * A0 + C1 * A1 + C2 * A2) / (Bd * Bd));
  }
}

extern "C" void kernel_launch(void* const* d_in, const int* in_sizes, int n_in,
                              void* d_out, int out_size, void* d_ws, size_t ws_size,
                              hipStream_t stream) {
  const float* s = (const float*)d_in[0];
  const int* t = (const int*)d_in[1];
  float* out = (float*)d_out;
  double* ws = (double*)d_ws;
  const int B = in_sizes[0] / NCLS;

  const int quanta = B >> 2;
  int nb = (quanta + K1_BLOCK - 1) / K1_BLOCK;  // 32 for B=8192
  if (nb < 1) nb = 1;
  if (nb > 256) nb = 256;  // grid-stride covers the rest; ws needs nb*6 doubles

  partial_kernel<<<dim3(nb), dim3(K1_BLOCK), 0, stream>>>(s, t, ws, B);
  finalize_kernel<<<dim3(1), dim3(64), 0, stream>>>(ws, out, B, nb);
}